// Round 10
// baseline (106.330 us; speedup 1.0000x reference)
//
#include <hip/hip_runtime.h>
#include <hip/hip_bf16.h>

#define BATCH 8192
#define DIM 64
#define TINV 5.0f              // 1 / TEMPERATURE
#define SCALE5 7.21347520444f  // 5 * log2(e): A pre-scale so MFMA acc = log2(exp(sim/T))
#define CGT 1.01831563889f     // 1 + e^-4
#define MARGIN 0.8f
#define LGAMMA 0.5f
#define LREG 1e-4f

typedef __attribute__((ext_vector_type(8))) short short8;
typedef __attribute__((ext_vector_type(4))) float float4v;

__device__ __forceinline__ unsigned short f2bf(float f) {
    unsigned int u = __builtin_bit_cast(unsigned int, f);
    unsigned int r = (u + 0x7fffu + ((u >> 16) & 1u)) >> 16;  // round-nearest-even
    return (unsigned short)r;
}

// Phase 1: ONE row per wave (lane = dim, scalar float loads: 64 lanes x 4 B =
// one 256 B coalesced read per table). 8192 waves = 32 waves/CU for max
// gather-latency hiding. Writes e1*SCALE5 row-major (A-frags) and g = e1+e2
// in the B-fragment-swizzled tile layout (8-lane groups write 16 contiguous
// bytes). Per-row pos/bpr/reg; zeroes total[] and out[0..2].
// grid: 2048 blocks x 256 thr = 8192 waves = 8192 rows.
__global__ __launch_bounds__(256) void phase1(
    const float* __restrict__ utab,
    const float* __restrict__ itab,
    const int* __restrict__ user, const int* __restrict__ posi,
    const int* __restrict__ negi,
    unsigned short* __restrict__ e1_out, unsigned short* __restrict__ g_sw,
    float* __restrict__ pos_score, float* __restrict__ row_bpr,
    float* __restrict__ row_reg, float* __restrict__ total,
    float* __restrict__ out)
{
    const int tid = blockIdx.x * 256 + threadIdx.x;
    if (tid < BATCH) total[tid] = 0.0f;   // done before phase2 (stream order)
    if (tid < 3) out[tid] = 0.0f;         // phase3 atomically accumulates

    const int lane = tid & 63;
    const int r    = tid >> 6;            // one row per wave

    const int ui = user[r], pi = posi[r], ni = negi[r];
    const float u = utab[(size_t)ui * DIM + lane];
    const float p = itab[(size_t)pi * DIM + lane];
    const float n = itab[(size_t)ni * DIM + lane];

    float up = u * p, un = u * n, uu = u * u, pp = p * p, nn = n * n;
    #pragma unroll
    for (int off = 1; off < 64; off <<= 1) {   // full-wave reduce (broadcasts)
        up += __shfl_xor(up, off);
        un += __shfl_xor(un, off);
        uu += __shfl_xor(uu, off);
        pp += __shfl_xor(pp, off);
        nn += __shfl_xor(nn, off);
    }
    const float ia = 1.0f / fmaxf(sqrtf(uu), 1e-12f);   // e1 = u * ia
    const float ib = 1.0f / fmaxf(sqrtf(pp), 1e-12f);   // e2 = p * ib

    e1_out[r * DIM + lane] = f2bf(u * (SCALE5 * ia));   // row-major (A-frags)

    // swizzled g write, scalar k = lane:
    // tile t = r>>6; within tile: ct = (r&63)>>4, rsel = r&15;
    // k: ks = k>>5, q = (k&31)>>3, j = k&7
    {
        const int t = r >> 6, m = r & 63;
        const int ct = m >> 4, rsel = m & 15;
        const int ks = lane >> 5, q = (lane & 31) >> 3, j = lane & 7;
        g_sw[t * 4096 + (ct * 2 + ks) * 512 + (q * 16 + rsel) * 8 + j] =
            f2bf(u * ia + p * ib);
    }

    if (lane == 0) {
        const float sim = up * (ia * ib);
        pos_score[r] = __expf(sim * TINV) + __expf(fmaxf(sim - MARGIN, 0.0f) * TINV);
        const float x = up - un;   // pos - neg (raw embeddings)
        row_bpr[r] = fmaxf(-x, 0.0f) + __logf(1.0f + __expf(-fabsf(x)));
        row_reg[r] = uu + pp + nn;
    }
}

// Phase 2: total[i] = sum_j f(e1_i . g_j) via bf16 MFMA, fused epilogue.
// A pre-scaled by 5*log2e so t = acc, e = 2^t (raw v_exp_f32), and
// f = e + max(e*e^-4, 1) = max(e*(1+e^-4), e+1).
// Each wave: 64 rows x 128 cols (rt=4, it=2). b-loads from the swizzled
// layout: one base + lane*16 + const offsets (no per-load address math).
// grid (128 row-stripes, 16 col-slices) x 256 thr (4 waves) = 2048 blocks
// = 8 blocks/CU = 32 waves/CU (VGPR ~60 -> 8/SIMD allowed). No min-waves
// bound (R7: forcing 8 clamps to 32 VGPR and spills).
__global__ __launch_bounds__(256) void phase2(
    const unsigned short* __restrict__ e1,
    const unsigned short* __restrict__ g_sw,
    float* __restrict__ total)
{
    const int w = threadIdx.x >> 6;         // wave in block
    const int lane = threadIdx.x & 63;
    const int r0 = blockIdx.x * 64;
    const int rowsel = lane & 15;
    const int kbase = (lane >> 4) * 8;      // A-frag: [m=lane&15][k=quad*8+j]

    short8 a[4][2];
    #pragma unroll
    for (int rt = 0; rt < 4; rt++)
        #pragma unroll
        for (int ks = 0; ks < 2; ks++)
            a[rt][ks] = *(const short8*)&e1[(r0 + rt * 16 + rowsel) * DIM + ks * 32 + kbase];

    float rowacc[4][4];
    #pragma unroll
    for (int rt = 0; rt < 4; rt++)
        #pragma unroll
        for (int q = 0; q < 4; q++) rowacc[rt][q] = 0.0f;

    const char* gbase = (const char*)g_sw + (size_t)lane * 16;

    #pragma unroll
    for (int it = 0; it < 2; it++) {
        const int t = blockIdx.y * 8 + w * 2 + it;      // 64-col tile index
        const char* bp = gbase + (size_t)t * 8192;
        short8 b[4][2];
        #pragma unroll
        for (int ct = 0; ct < 4; ct++)
            #pragma unroll
            for (int ks = 0; ks < 2; ks++)
                b[ct][ks] = *(const short8*)(bp + (ct * 2 + ks) * 1024);

        #pragma unroll
        for (int rt = 0; rt < 4; rt++) {
            #pragma unroll
            for (int ct = 0; ct < 4; ct++) {
                float4v acc = {0.0f, 0.0f, 0.0f, 0.0f};
                acc = __builtin_amdgcn_mfma_f32_16x16x32_bf16(a[rt][0], b[ct][0], acc, 0, 0, 0);
                acc = __builtin_amdgcn_mfma_f32_16x16x32_bf16(a[rt][1], b[ct][1], acc, 0, 0, 0);
                #pragma unroll
                for (int q = 0; q < 4; q++) {
                    const float e = __builtin_amdgcn_exp2f(acc[q]);  // raw v_exp_f32
                    rowacc[rt][q] += fmaxf(e * CGT, e + 1.0f);
                }
            }
        }
    }

    // reduce across the 16 column-lanes (same lane>>4 group holds same rows)
    #pragma unroll
    for (int off = 1; off < 16; off <<= 1)
        #pragma unroll
        for (int rt = 0; rt < 4; rt++)
            #pragma unroll
            for (int q = 0; q < 4; q++)
                rowacc[rt][q] += __shfl_xor(rowacc[rt][q], off);

    if ((lane & 15) == 0) {
        const int rquad = lane >> 4;  // C/D layout: row = quad*4 + q
        #pragma unroll
        for (int rt = 0; rt < 4; rt++)
            #pragma unroll
            for (int q = 0; q < 4; q++)
                atomicAdd(&total[r0 + rt * 16 + rquad * 4 + q], rowacc[rt][q]);
    }
}

// Phase 3: final reductions -> out[0..2] (float32: bpr, reg, na), atomic merge.
// 8 blocks x 1024 thr, one row per thread. out was zeroed by phase1.
__global__ __launch_bounds__(1024) void phase3(
    const float* __restrict__ pos_score, const float* __restrict__ total,
    const float* __restrict__ row_bpr, const float* __restrict__ row_reg,
    float* __restrict__ out)
{
    const int i = blockIdx.x * 1024 + threadIdx.x;
    float sb = row_bpr[i];
    float sr = row_reg[i];
    float sn = -__logf(pos_score[i] / total[i] + 1e-5f);
    #pragma unroll
    for (int off = 32; off; off >>= 1) {
        sb += __shfl_xor(sb, off);
        sr += __shfl_xor(sr, off);
        sn += __shfl_xor(sn, off);
    }
    __shared__ float rb[16], rr[16], rn[16];
    const int wid = threadIdx.x >> 6;
    if ((threadIdx.x & 63) == 0) { rb[wid] = sb; rr[wid] = sr; rn[wid] = sn; }
    __syncthreads();
    if (threadIdx.x == 0) {
        float tb = 0.0f, tr = 0.0f, tn = 0.0f;
        #pragma unroll
        for (int k = 0; k < 16; k++) { tb += rb[k]; tr += rr[k]; tn += rn[k]; }
        atomicAdd(&out[0], tb / (float)BATCH);
        atomicAdd(&out[1], LREG * 0.5f * tr / (float)BATCH);
        atomicAdd(&out[2], LGAMMA * tn / (float)BATCH);
    }
}

extern "C" void kernel_launch(void* const* d_in, const int* in_sizes, int n_in,
                              void* d_out, int out_size, void* d_ws, size_t ws_size,
                              hipStream_t stream) {
    const float* utab = (const float*)d_in[0];  // float32 [100000,64]
    const float* itab = (const float*)d_in[1];  // float32 [50000,64]
    const int* user = (const int*)d_in[2];
    const int* posi = (const int*)d_in[3];
    const int* negi = (const int*)d_in[4];

    char* ws = (char*)d_ws;
    unsigned short* e1   = (unsigned short*)ws;                              // 1 MiB
    unsigned short* g_sw = (unsigned short*)(ws + (size_t)BATCH * DIM * 2);  // 1 MiB
    float* pos_score     = (float*)(ws + 2 * (size_t)BATCH * DIM * 2);       // 32 KiB
    float* total         = pos_score + BATCH;                                // 32 KiB
    float* row_bpr       = total + BATCH;                                    // 32 KiB
    float* row_reg       = row_bpr + BATCH;                                  // 32 KiB

    phase1<<<2048, 256, 0, stream>>>(utab, itab, user, posi, negi,
                                     e1, g_sw, pos_score, row_bpr, row_reg,
                                     total, (float*)d_out);
    phase2<<<dim3(128, 16), 256, 0, stream>>>(e1, g_sw, total);
    phase3<<<8, 1024, 0, stream>>>(pos_score, total, row_bpr, row_reg,
                                   (float*)d_out);
}

// Round 11
// 102.078 us; speedup vs baseline: 1.0417x; 1.0417x over previous
//
#include <hip/hip_runtime.h>
#include <hip/hip_bf16.h>

#define BATCH 8192
#define DIM 64
#define TINV 5.0f              // 1 / TEMPERATURE
#define SCALE5 7.21347520444f  // 5 * log2(e): A pre-scale so MFMA acc = log2(exp(sim/T))
#define CGT 1.01831563889f     // 1 + e^-4
#define MARGIN 0.8f
#define LGAMMA 0.5f
#define LREG 1e-4f

typedef __attribute__((ext_vector_type(8))) short short8;
typedef __attribute__((ext_vector_type(4))) float float4v;
typedef __attribute__((ext_vector_type(2))) float float2v;

__device__ __forceinline__ unsigned short f2bf(float f) {
    unsigned int u = __builtin_bit_cast(unsigned int, f);
    unsigned int r = (u + 0x7fffu + ((u >> 16) & 1u)) >> 16;  // round-nearest-even
    return (unsigned short)r;
}

// Phase 1 (R9-measured config): 4 rows/wave (float4/lane, 16-lane groups).
// Gathers ue/pe/ne, writes e1*SCALE5 row-major (A-frags) and g = e1+e2 in the
// MFMA-B-fragment-swizzled tile layout. Per-row pos/bpr/reg; zeroes total[]
// and out[0..2]. grid: 512 blocks x 256 thr = 2048 waves = 8192 rows.
__global__ __launch_bounds__(256) void phase1(
    const float* __restrict__ utab,
    const float* __restrict__ itab,
    const int* __restrict__ user, const int* __restrict__ posi,
    const int* __restrict__ negi,
    unsigned short* __restrict__ e1_out, unsigned short* __restrict__ g_sw,
    float* __restrict__ pos_score, float* __restrict__ row_bpr,
    float* __restrict__ row_reg, float* __restrict__ total,
    float* __restrict__ out)
{
    const int tid = blockIdx.x * 256 + threadIdx.x;
    if (tid < BATCH) total[tid] = 0.0f;   // done before phase2 (stream order)
    if (tid < 3) out[tid] = 0.0f;         // phase3 atomically accumulates

    const int lane = threadIdx.x & 63;
    const int l16  = lane & 15;
    const int r    = (tid >> 6) * 4 + (lane >> 4);

    const int ui = user[r], pi = posi[r], ni = negi[r];
    const float4 u = *(const float4*)&utab[(size_t)ui * DIM + l16 * 4];
    const float4 p = *(const float4*)&itab[(size_t)pi * DIM + l16 * 4];
    const float4 n = *(const float4*)&itab[(size_t)ni * DIM + l16 * 4];

    float up = u.x*p.x + u.y*p.y + u.z*p.z + u.w*p.w;
    float un = u.x*n.x + u.y*n.y + u.z*n.z + u.w*n.w;
    float uu = u.x*u.x + u.y*u.y + u.z*u.z + u.w*u.w;
    float pp = p.x*p.x + p.y*p.y + p.z*p.z + p.w*p.w;
    float nn = n.x*n.x + n.y*n.y + n.z*n.z + n.w*n.w;
    #pragma unroll
    for (int off = 1; off < 16; off <<= 1) {   // reduce within 16-lane group
        up += __shfl_xor(up, off);
        un += __shfl_xor(un, off);
        uu += __shfl_xor(uu, off);
        pp += __shfl_xor(pp, off);
        nn += __shfl_xor(nn, off);
    }
    const float ia = 1.0f / fmaxf(sqrtf(uu), 1e-12f);   // e1 = u * ia
    const float ib = 1.0f / fmaxf(sqrtf(pp), 1e-12f);   // e2 = p * ib
    const float sa = SCALE5 * ia;

    union { unsigned short h[4]; uint2 v; } pa, pg;
    pa.h[0] = f2bf(u.x * sa); pa.h[1] = f2bf(u.y * sa);
    pa.h[2] = f2bf(u.z * sa); pa.h[3] = f2bf(u.w * sa);
    pg.h[0] = f2bf(u.x * ia + p.x * ib); pg.h[1] = f2bf(u.y * ia + p.y * ib);
    pg.h[2] = f2bf(u.z * ia + p.z * ib); pg.h[3] = f2bf(u.w * ia + p.w * ib);

    *(uint2*)&e1_out[r * DIM + l16 * 4] = pa.v;   // row-major (A-frags)

    // swizzled g write: lane l16 covers k in [l16*4, l16*4+4)
    {
        const int t = r >> 6, m = r & 63;
        const int ct = m >> 4, rsel = m & 15;
        const int ks = l16 >> 3, q = (l16 & 7) >> 1, half = l16 & 1;
        const int off = t * 4096 + (ct * 2 + ks) * 512 + (q * 16 + rsel) * 8 + half * 4;
        *(uint2*)&g_sw[off] = pg.v;
    }

    if (l16 == 0) {
        const float sim = up * (ia * ib);
        pos_score[r] = __expf(sim * TINV) + __expf(fmaxf(sim - MARGIN, 0.0f) * TINV);
        const float x = up - un;   // pos - neg (raw embeddings)
        row_bpr[r] = fmaxf(-x, 0.0f) + __logf(1.0f + __expf(-fabsf(x)));
        row_reg[r] = uu + pp + nn;
    }
}

// Phase 2: total[i] = sum_j f(e1_i . g_j) via bf16 MFMA, fused epilogue.
// A pre-scaled by 5*log2e so t = acc, e = 2^t (raw v_exp_f32), and
// f = e + max(e*e^-4, 1) = max(e*(1+e^-4), e+1), evaluated as PACKED float2
// (v_pk_mul/add/max) to halve the non-exp epilogue VALU issue.
// Each wave: 64 rows x 256 cols (rt=4, it=4). b-loads from the swizzled
// layout: one base + lane*16 + const offsets (no per-load address math).
// grid (128 row-stripes, 8 col-slices) x 256 thr (4 waves) — R9-measured.
__global__ __launch_bounds__(256) void phase2(
    const unsigned short* __restrict__ e1,
    const unsigned short* __restrict__ g_sw,
    float* __restrict__ total)
{
    const int w = threadIdx.x >> 6;         // wave in block
    const int lane = threadIdx.x & 63;
    const int r0 = blockIdx.x * 64;
    const int rowsel = lane & 15;
    const int kbase = (lane >> 4) * 8;      // A-frag: [m=lane&15][k=quad*8+j]

    short8 a[4][2];
    #pragma unroll
    for (int rt = 0; rt < 4; rt++)
        #pragma unroll
        for (int ks = 0; ks < 2; ks++)
            a[rt][ks] = *(const short8*)&e1[(r0 + rt * 16 + rowsel) * DIM + ks * 32 + kbase];

    float2v rowacc[4][2];                   // q-pairs, packed
    #pragma unroll
    for (int rt = 0; rt < 4; rt++)
        #pragma unroll
        for (int p = 0; p < 2; p++) rowacc[rt][p] = (float2v){0.0f, 0.0f};

    const char* gbase = (const char*)g_sw + (size_t)lane * 16;

    for (int it = 0; it < 4; it++) {
        const int t = blockIdx.y * 16 + w * 4 + it;     // 64-col tile index
        const char* bp = gbase + (size_t)t * 8192;
        short8 b[4][2];
        #pragma unroll
        for (int ct = 0; ct < 4; ct++)
            #pragma unroll
            for (int ks = 0; ks < 2; ks++)
                b[ct][ks] = *(const short8*)(bp + (ct * 2 + ks) * 1024);

        #pragma unroll
        for (int rt = 0; rt < 4; rt++) {
            #pragma unroll
            for (int ct = 0; ct < 4; ct++) {
                float4v acc = {0.0f, 0.0f, 0.0f, 0.0f};
                acc = __builtin_amdgcn_mfma_f32_16x16x32_bf16(a[rt][0], b[ct][0], acc, 0, 0, 0);
                acc = __builtin_amdgcn_mfma_f32_16x16x32_bf16(a[rt][1], b[ct][1], acc, 0, 0, 0);
                #pragma unroll
                for (int p = 0; p < 2; p++) {
                    float2v e;
                    e.x = __builtin_amdgcn_exp2f(acc[p * 2 + 0]);
                    e.y = __builtin_amdgcn_exp2f(acc[p * 2 + 1]);
                    rowacc[rt][p] += __builtin_elementwise_max(e * CGT, e + 1.0f);
                }
            }
        }
    }

    // reduce across the 16 column-lanes (same lane>>4 group holds same rows)
    #pragma unroll
    for (int off = 1; off < 16; off <<= 1)
        #pragma unroll
        for (int rt = 0; rt < 4; rt++)
            #pragma unroll
            for (int p = 0; p < 2; p++) {
                float2v o;
                o.x = __shfl_xor(rowacc[rt][p].x, off);
                o.y = __shfl_xor(rowacc[rt][p].y, off);
                rowacc[rt][p] += o;
            }

    if ((lane & 15) == 0) {
        const int rquad = lane >> 4;  // C/D layout: row = quad*4 + q
        #pragma unroll
        for (int rt = 0; rt < 4; rt++)
            #pragma unroll
            for (int p = 0; p < 2; p++) {
                atomicAdd(&total[r0 + rt * 16 + rquad * 4 + p * 2 + 0], rowacc[rt][p].x);
                atomicAdd(&total[r0 + rt * 16 + rquad * 4 + p * 2 + 1], rowacc[rt][p].y);
            }
    }
}

// Phase 3: final reductions -> out[0..2] (float32: bpr, reg, na), atomic merge.
// 8 blocks x 1024 thr, one row per thread. out was zeroed by phase1.
__global__ __launch_bounds__(1024) void phase3(
    const float* __restrict__ pos_score, const float* __restrict__ total,
    const float* __restrict__ row_bpr, const float* __restrict__ row_reg,
    float* __restrict__ out)
{
    const int i = blockIdx.x * 1024 + threadIdx.x;
    float sb = row_bpr[i];
    float sr = row_reg[i];
    float sn = -__logf(pos_score[i] / total[i] + 1e-5f);
    #pragma unroll
    for (int off = 32; off; off >>= 1) {
        sb += __shfl_xor(sb, off);
        sr += __shfl_xor(sr, off);
        sn += __shfl_xor(sn, off);
    }
    __shared__ float rb[16], rr[16], rn[16];
    const int wid = threadIdx.x >> 6;
    if ((threadIdx.x & 63) == 0) { rb[wid] = sb; rr[wid] = sr; rn[wid] = sn; }
    __syncthreads();
    if (threadIdx.x == 0) {
        float tb = 0.0f, tr = 0.0f, tn = 0.0f;
        #pragma unroll
        for (int k = 0; k < 16; k++) { tb += rb[k]; tr += rr[k]; tn += rn[k]; }
        atomicAdd(&out[0], tb / (float)BATCH);
        atomicAdd(&out[1], LREG * 0.5f * tr / (float)BATCH);
        atomicAdd(&out[2], LGAMMA * tn / (float)BATCH);
    }
}

extern "C" void kernel_launch(void* const* d_in, const int* in_sizes, int n_in,
                              void* d_out, int out_size, void* d_ws, size_t ws_size,
                              hipStream_t stream) {
    const float* utab = (const float*)d_in[0];  // float32 [100000,64]
    const float* itab = (const float*)d_in[1];  // float32 [50000,64]
    const int* user = (const int*)d_in[2];
    const int* posi = (const int*)d_in[3];
    const int* negi = (const int*)d_in[4];

    char* ws = (char*)d_ws;
    unsigned short* e1   = (unsigned short*)ws;                              // 1 MiB
    unsigned short* g_sw = (unsigned short*)(ws + (size_t)BATCH * DIM * 2);  // 1 MiB
    float* pos_score     = (float*)(ws + 2 * (size_t)BATCH * DIM * 2);       // 32 KiB
    float* total         = pos_score + BATCH;                                // 32 KiB
    float* row_bpr       = total + BATCH;                                    // 32 KiB
    float* row_reg       = row_bpr + BATCH;                                  // 32 KiB

    phase1<<<512, 256, 0, stream>>>(utab, itab, user, posi, negi,
                                    e1, g_sw, pos_score, row_bpr, row_reg,
                                    total, (float*)d_out);
    phase2<<<dim3(128, 8), 256, 0, stream>>>(e1, g_sw, total);
    phase3<<<8, 1024, 0, stream>>>(pos_score, total, row_bpr, row_reg,
                                   (float*)d_out);
}